// Round 1
// baseline (881.749 us; speedup 1.0000x reference)
//
#include <hip/hip_runtime.h>
#include <math.h>

#define NN 50000
#define EE 800000
#define EEN (EE+NN)          // edges + self loops
#define STRIDE 64            // fixed CSR stride: self + up to 63 in-edges
#define NFEAT 4
#define EFEAT 4
#define EMBD 16
#define IN0 20   // NF + EMB
#define HIDD 64
#define OUTD 128

// bf16 helpers: storage = unsigned short, RTN-even pack, shift-decode
__device__ __forceinline__ unsigned short f2bf(float f){
  unsigned u = __float_as_uint(f);
  return (unsigned short)((u + 0x7FFFu + ((u>>16)&1u)) >> 16);
}
__device__ __forceinline__ float bfl(unsigned u){ return __uint_as_float(u<<16); }
__device__ __forceinline__ float bfh(unsigned u){ return __uint_as_float(u & 0xFFFF0000u); }

template<int V> struct ldt;
template<> struct ldt<4>{ using T = uint2; };
template<> struct ldt<2>{ using T = unsigned int; };

// ---------------- init: zero fill ----------------
__global__ void k_init(int* fill){
  int i = blockIdx.x*blockDim.x + threadIdx.x;
  if (i < NN) fill[i]=0;
}

// ---------------- fixed-stride CSR scatter (one kernel, no scan) ----------
// col[n*64] = n (self); col[n*64+1+k] = src. NEW (R10): eattr is ALSO
// scattered into CSR slot order (eacsr) so the per-layer edge pass can run
// in slot order with pure streaming reads/writes. The 16B random-write RFO
// cost is paid ONCE here instead of 3x in k_edge (which previously scatter-
// wrote pp to random slots every layer). epos is gone entirely.
__global__ void k_scatter(const int* __restrict__ ei, const float4* __restrict__ eattr,
                          int* fill, int* __restrict__ col, float4* __restrict__ eacsr){
  int idx = blockIdx.x*blockDim.x + threadIdx.x;
  if (idx < EE){
    int d = ei[EE+idx];
    int pos = atomicAdd(&fill[d],1);
    int slot = d*STRIDE + 1 + pos;
    col[slot] = ei[idx];
    eacsr[slot] = eattr[idx];
  } else if (idx < EEN){
    int n = idx-EE;
    col[n*STRIDE] = n;
  }
}

// ---------------- av (all 3 layers) + zred init, one launch ----------------
template<int F_IN,int HH,int CC>
__device__ __forceinline__ void av_one(const float* W, const float* asrc,
                                       const float* adst, float* av, int tid){
  if (tid >= HH*F_IN) return;
  int h = tid / F_IN, f = tid % F_IN;
  float s1=0.f, s2=0.f;
  for (int c=0;c<CC;c++){
    float wv = W[(size_t)(h*CC+c)*F_IN+f];
    s1 += asrc[h*CC+c]*wv;
    s2 += adst[h*CC+c]*wv;
  }
  av[tid] = s1;
  av[HH*F_IN+tid] = s2;
}
__global__ void k_av3(const float* W0, const float* as0, const float* ad0, float* av0,
                      const float* W1, const float* as1, const float* ad1, float* av1,
                      const float* W2, const float* as2, const float* ad2, float* av2,
                      float* zred){
  int tid = threadIdx.x;
  if      (blockIdx.x==0){ av_one<IN0,4,64> (W0, as0, ad0, av0, tid); if (tid<24) zred[tid]=0.f; }
  else if (blockIdx.x==1) av_one<64,4,64>  (W1, as1, ad1, av1, tid);
  else                    av_one<64,1,128> (W2, as2, ad2, av2, tid);
}

// ---------------- outer-product register-tiled GEMM + fused scores --------
template<int K,int NCOL,int HH,bool CONCAT>
__global__ __launch_bounds__(256)
void k_gemm(const float* __restrict__ xin, const int* __restrict__ jt,
            const float* __restrict__ emb, const float* __restrict__ W,
            const float* __restrict__ avp, unsigned short* __restrict__ hout,
            float* __restrict__ si, float* __restrict__ sj){
  constexpr int PITCH = 132;
  __shared__ float xT[K*PITCH];
  __shared__ float wT[K*PITCH];
  __shared__ float EMBL[CONCAT ? 17*EMBD : 1];
  int tid = threadIdx.x;
  int rbase = blockIdx.x*128, cbase = blockIdx.y*128;
  if (CONCAT){
    for (int i=tid; i<17*EMBD; i+=256) EMBL[i]=emb[i];
    __syncthreads();
    if (tid < 128){
      int row = tid;
      int gr = rbase+row; if (gr >= NN) gr = NN-1;
      float4 v = ((const float4*)xin)[gr];
      xT[0*PITCH+row]=v.x; xT[1*PITCH+row]=v.y;
      xT[2*PITCH+row]=v.z; xT[3*PITCH+row]=v.w;
      int j = jt[gr];
      #pragma unroll
      for (int k=0;k<EMBD;k++) xT[(NFEAT+k)*PITCH+row] = EMBL[j*EMBD+k];
    } else {
      int col = tid-128;
      const float4* wp = (const float4*)(W + (size_t)(cbase+col)*K);
      #pragma unroll
      for (int k4=0;k4<K/4;k4++){
        float4 v = wp[k4];
        wT[(4*k4+0)*PITCH+col]=v.x; wT[(4*k4+1)*PITCH+col]=v.y;
        wT[(4*k4+2)*PITCH+col]=v.z; wT[(4*k4+3)*PITCH+col]=v.w;
      }
    }
  } else {
    constexpr int K4 = K/4;
    for (int i=tid; i<128*K4; i+=256){
      int row = i/K4, k4 = i%K4;
      int gr = rbase+row; if (gr >= NN) gr = NN-1;
      float4 v = ((const float4*)xin)[(size_t)gr*K4 + k4];
      xT[(4*k4+0)*PITCH+row]=v.x; xT[(4*k4+1)*PITCH+row]=v.y;
      xT[(4*k4+2)*PITCH+row]=v.z; xT[(4*k4+3)*PITCH+row]=v.w;
    }
    for (int i=tid; i<128*K4; i+=256){
      int col = i/K4, k4 = i%K4;
      float4 v = ((const float4*)W)[(size_t)(cbase+col)*K4 + k4];
      wT[(4*k4+0)*PITCH+col]=v.x; wT[(4*k4+1)*PITCH+col]=v.y;
      wT[(4*k4+2)*PITCH+col]=v.z; wT[(4*k4+3)*PITCH+col]=v.w;
    }
  }
  __syncthreads();
  int lane = tid & 63, w = tid >> 6;
  int r0 = (w>>1)*64 + (lane&7)*8;
  int c0 = (w&1)*64 + (lane>>3)*8;
  float acc[8][8];
  #pragma unroll
  for (int i=0;i<8;i++)
    #pragma unroll
    for (int j=0;j<8;j++) acc[i][j]=0.f;
  #pragma unroll 4
  for (int k=0;k<K;k++){
    float a[8], b[8];
    *(float4*)&a[0] = *(const float4*)&xT[k*PITCH + r0];
    *(float4*)&a[4] = *(const float4*)&xT[k*PITCH + r0 + 4];
    *(float4*)&b[0] = *(const float4*)&wT[k*PITCH + c0];
    *(float4*)&b[4] = *(const float4*)&wT[k*PITCH + c0 + 4];
    #pragma unroll
    for (int i=0;i<8;i++)
      #pragma unroll
      for (int j=0;j<8;j++) acc[i][j] += a[i]*b[j];
  }
  if (blockIdx.y==0 && tid < 128){
    int row = tid, gr = rbase+row;
    if (gr < NN){
      #pragma unroll
      for (int h=0;h<HH;h++){
        float a=0.f, b=0.f;
        for (int k=0;k<K;k++){
          float xv = xT[k*PITCH+row];
          a += xv*avp[h*K+k];
          b += xv*avp[HH*K+h*K+k];
        }
        si[(size_t)gr*HH+h]=a;
        sj[(size_t)gr*HH+h]=b;
      }
    }
  }
  #pragma unroll
  for (int i=0;i<8;i++){
    int n = rbase + r0 + i;
    if (n < NN){
      uint4 o;
      o.x = (unsigned)f2bf(acc[i][0]) | ((unsigned)f2bf(acc[i][1])<<16);
      o.y = (unsigned)f2bf(acc[i][2]) | ((unsigned)f2bf(acc[i][3])<<16);
      o.z = (unsigned)f2bf(acc[i][4]) | ((unsigned)f2bf(acc[i][5])<<16);
      o.w = (unsigned)f2bf(acc[i][6]) | ((unsigned)f2bf(acc[i][7])<<16);
      *(uint4*)(hout + (size_t)n*NCOL + cbase + c0) = o;
    }
  }
}

// ---------------- slot-order edge pass: exp(lrelu(score)) + per-head sum ----
// R10: iterate CSR slots, not original edges. Wave per node, lane = slot.
// col (4B) / eacsr (16B) reads stream; pp write is coalesced-contiguous per
// node (no RFO scatter). si[n] is a wave-broadcast; only sj[src] is a random
// gather, but sj is 800KB -> L2-resident. lane 0 is the self loop (eattr=0).
template<int HH>
__global__ __launch_bounds__(256)
void k_edge2(const int* __restrict__ col, const float4* __restrict__ eacsr,
             const int* __restrict__ fill, const float* __restrict__ We,
             const float* __restrict__ si, const float* __restrict__ sj,
             float* __restrict__ pp, float* __restrict__ zred){
  int wave = threadIdx.x>>6, lane = threadIdx.x&63;
  int n = blockIdx.x*4 + wave;           // NN % 4 == 0
  int cnt = 1 + fill[n];                 // active slots: self + in-edges
  float z[HH];
  #pragma unroll
  for (int h=0;h<HH;h++) z[h]=0.f;
  if (lane < cnt){
    int slot = n*STRIDE + lane;
    int s = col[slot];
    float4 ea;
    if (lane==0){ ea = make_float4(0.f,0.f,0.f,0.f); }
    else        { ea = eacsr[slot]; }
    if (HH==4){
      float4 siv = ((const float4*)si)[n];
      float4 sjv = ((const float4*)sj)[s];
      float te[4] = {siv.x+sjv.x, siv.y+sjv.y, siv.z+sjv.z, siv.w+sjv.w};
      float pv[4];
      #pragma unroll
      for (int h=0;h<4;h++){
        float t = te[h] + ea.x*We[h*EFEAT+0] + ea.y*We[h*EFEAT+1]
                        + ea.z*We[h*EFEAT+2] + ea.w*We[h*EFEAT+3];
        t = (t>0.f)? t : 0.2f*t;
        float p = expf(t);
        z[h]=p; pv[h]=p;
      }
      ((float4*)pp)[slot] = make_float4(pv[0],pv[1],pv[2],pv[3]);
    } else {
      float t = si[n] + sj[s]
              + ea.x*We[0] + ea.y*We[1] + ea.z*We[2] + ea.w*We[3];
      t = (t>0.f)? t : 0.2f*t;
      float p = expf(t);
      z[0]=p;
      pp[slot] = p;
    }
  }
  __shared__ float zs[4][HH];
  #pragma unroll
  for (int h=0;h<HH;h++){
    float v=z[h];
    #pragma unroll
    for (int off=32; off>0; off>>=1) v += __shfl_xor(v,off,64);
    if (lane==0) zs[wave][h]=v;
  }
  __syncthreads();
  if (threadIdx.x < HH){
    float tot = zs[0][threadIdx.x]+zs[1][threadIdx.x]
              + zs[2][threadIdx.x]+zs[3][threadIdx.x];
    atomicAdd(&zred[threadIdx.x], tot);
  }
}

// ---------------- pull-mode aggregation, wave-per-node, bf16 gather --------
// R6-proven access shape: col (4B) + pp (CSR-ordered) stream; only h is a
// random gather. 8-edge unroll + remainder. UNTOUCHED in R10.
template<int HH,int CC,bool DO_ELU>
__global__ __launch_bounds__(256)
void k_agg(const unsigned short* __restrict__ hb, const float* __restrict__ pp,
           const float* __restrict__ zred, const int* __restrict__ fill,
           const int* __restrict__ col, float* __restrict__ outp){
  constexpr int HC = HH*CC;
  constexpr int V  = HC/64;
  using LT = typename ldt<V>::T;
  int wave = threadIdx.x>>6, lane = threadIdx.x&63;
  int n = blockIdx.x*4 + wave;           // NN % 4 == 0
  int hd = (lane*V)/CC;
  float invZ = 1.0f/zred[hd];
  float acc[V];
  #pragma unroll
  for (int v=0;v<V;v++) acc[v]=0.f;
  auto mac = [&](float p, LT h){
    if constexpr (V==4){
      acc[0] += p*bfl(h.x); acc[1] += p*bfh(h.x);
      acc[2] += p*bfl(h.y); acc[3] += p*bfh(h.y);
    } else {
      acc[0] += p*bfl(h);   acc[1] += p*bfh(h);
    }
  };
  int beg = n*STRIDE, end = beg + 1 + fill[n];
  int i = beg;
  for (; i+8<=end; i+=8){
    int sr[8]; float p[8]; LT h[8];
    #pragma unroll
    for (int k=0;k<8;k++) sr[k]=col[i+k];
    #pragma unroll
    for (int k=0;k<8;k++)
      p[k] = (HH==4) ? pp[(size_t)(i+k)*4+hd] : pp[i+k];
    #pragma unroll
    for (int k=0;k<8;k++) h[k]=((const LT*)(hb + (size_t)sr[k]*HC))[lane];
    #pragma unroll
    for (int k=0;k<8;k++) mac(p[k], h[k]);
  }
  for (; i<end; i++){
    int sr = col[i];
    float p = (HH==4) ? pp[(size_t)i*4+hd] : pp[i];
    LT h = ((const LT*)(hb + (size_t)sr*HC))[lane];
    mac(p, h);
  }
  #pragma unroll
  for (int v=0;v<V;v++) acc[v] *= invZ;
  if (HH==4){
    #pragma unroll
    for (int off=16; off<64; off<<=1){
      #pragma unroll
      for (int v=0;v<V;v++) acc[v] += __shfl_xor(acc[v], off, 64);
    }
    if (lane < 16){
      float4 o;
      o.x=0.25f*acc[0]; o.y=0.25f*acc[1]; o.z=0.25f*acc[2]; o.w=0.25f*acc[3];
      if (DO_ELU){
        o.x = (o.x>0.f)? o.x : expm1f(o.x);
        o.y = (o.y>0.f)? o.y : expm1f(o.y);
        o.z = (o.z>0.f)? o.z : expm1f(o.z);
        o.w = (o.w>0.f)? o.w : expm1f(o.w);
      }
      ((float4*)outp)[(size_t)n*(CC/4)+lane] = o;
    }
  } else {
    float2 o; o.x=acc[0]; o.y=acc[1];
    if (DO_ELU){
      o.x = (o.x>0.f)? o.x : expm1f(o.x);
      o.y = (o.y>0.f)? o.y : expm1f(o.y);
    }
    ((float2*)outp)[(size_t)n*(CC/2)+lane] = o;
  }
}

extern "C" void kernel_launch(void* const* d_in, const int* in_sizes, int n_in,
                              void* d_out, int out_size, void* d_ws, size_t ws_size,
                              hipStream_t stream){
  const float* x    = (const float*)d_in[0];
  const int*   ei   = (const int*)d_in[1];
  const float* eatt = (const float*)d_in[2];
  const int*   jt   = (const int*)d_in[3];
  const float* emb  = (const float*)d_in[4];
  const float* W0   = (const float*)d_in[5];
  const float* as0  = (const float*)d_in[6];
  const float* ad0  = (const float*)d_in[7];
  const float* We0  = (const float*)d_in[8];
  const float* W1   = (const float*)d_in[9];
  const float* as1  = (const float*)d_in[10];
  const float* ad1  = (const float*)d_in[11];
  const float* We1  = (const float*)d_in[12];
  const float* W2   = (const float*)d_in[13];
  const float* as2  = (const float*)d_in[14];
  const float* ad2  = (const float*)d_in[15];
  const float* We2  = (const float*)d_in[16];
  float* out = (float*)d_out;

  char* p = (char*)d_ws;
  auto alloc = [&](size_t bytes)->char*{
    char* r = p; p += (bytes + 255) & ~(size_t)255; return r;
  };
  unsigned short* hbuf = (unsigned short*)alloc((size_t)NN*256*2); // 25.6 MB bf16
  float* x1     = (float*)alloc((size_t)NN*64*4);
  float* x2     = (float*)alloc((size_t)NN*64*4);
  float* si     = (float*)alloc((size_t)NN*4*4);
  float* sj     = (float*)alloc((size_t)NN*4*4);
  float* pp     = (float*)alloc((size_t)NN*STRIDE*16); // 51.2 MB CSR-slot alphas
  int*   fill   = (int*)alloc((size_t)NN*4);
  int*   col    = (int*)alloc((size_t)NN*STRIDE*4);    // 12.8 MB fixed-stride CSR
  float4* eacsr = (float4*)alloc((size_t)NN*STRIDE*16);// 51.2 MB CSR-slot eattr
  float* av0    = (float*)alloc(512*4);
  float* av1    = (float*)alloc(512*4);
  float* av2    = (float*)alloc(512*4);
  float* zred   = (float*)alloc(3*8*4);

  k_init   <<<dim3((NN+255)/256),  256, 0, stream>>>(fill);
  k_scatter<<<dim3((EEN+255)/256), 256, 0, stream>>>(ei, (const float4*)eatt,
                                                     fill, col, eacsr);
  k_av3    <<<dim3(3),             256, 0, stream>>>(W0,as0,ad0,av0, W1,as1,ad1,av1,
                                                     W2,as2,ad2,av2, zred);

  dim3 gg01((NN+127)/128, 2);
  dim3 gg2 ((NN+127)/128, 1);
  dim3 ngrid(NN/4);

  // layer 0: concat(x, emb[jt]) -> [N,4,64]
  k_gemm<IN0,256,4,true> <<<gg01, 256, 0, stream>>>(x, jt, emb, W0, av0, hbuf, si, sj);
  k_edge2<4>             <<<ngrid,256, 0, stream>>>(col, eacsr, fill, We0, si, sj, pp, zred+0);
  k_agg<4,64,true>       <<<ngrid,256, 0, stream>>>(hbuf, pp, zred+0, fill, col, x1);

  // layer 1: 64 -> [N,4,64]
  k_gemm<64,256,4,false> <<<gg01, 256, 0, stream>>>(x1, jt, emb, W1, av1, hbuf, si, sj);
  k_edge2<4>             <<<ngrid,256, 0, stream>>>(col, eacsr, fill, We1, si, sj, pp, zred+8);
  k_agg<4,64,true>       <<<ngrid,256, 0, stream>>>(hbuf, pp, zred+8, fill, col, x2);

  // layer 2: 64 -> [N,1,128], no ELU on final output
  k_gemm<64,128,1,false> <<<gg2,  256, 0, stream>>>(x2, jt, emb, W2, av2, hbuf, si, sj);
  k_edge2<1>             <<<ngrid,256, 0, stream>>>(col, eacsr, fill, We2, si, sj, pp, zred+16);
  k_agg<1,128,false>     <<<ngrid,256, 0, stream>>>(hbuf, pp, zred+16, fill, col, out);
}

// Round 3
// 495.476 us; speedup vs baseline: 1.7796x; 1.7796x over previous
//
#include <hip/hip_runtime.h>
#include <math.h>

#define NN 50000
#define EE 800000
#define EEN (EE+NN)          // edges + self loops
#define STRIDE 64            // fixed CSR stride: self + up to 63 in-edges
#define NFEAT 4
#define EFEAT 4
#define EMBD 16
#define IN0 20   // NF + EMB
#define HIDD 64
#define OUTD 128
#define EDGE_NB 1024         // k_edge2 grid: grid-stride, few blocks -> few atomics

// bf16 helpers: storage = unsigned short, RTN-even pack, shift-decode
__device__ __forceinline__ unsigned short f2bf(float f){
  unsigned u = __float_as_uint(f);
  return (unsigned short)((u + 0x7FFFu + ((u>>16)&1u)) >> 16);
}
__device__ __forceinline__ float bfl(unsigned u){ return __uint_as_float(u<<16); }
__device__ __forceinline__ float bfh(unsigned u){ return __uint_as_float(u & 0xFFFF0000u); }

template<int V> struct ldt;
template<> struct ldt<4>{ using T = uint2; };
template<> struct ldt<2>{ using T = unsigned int; };

// ---------------- init: zero fill ----------------
__global__ void k_init(int* fill){
  int i = blockIdx.x*blockDim.x + threadIdx.x;
  if (i < NN) fill[i]=0;
}

// ---------------- fixed-stride CSR scatter (one kernel, no scan) ----------
// col[n*64] = n (self); col[n*64+1+k] = src. eattr is ALSO scattered into
// CSR slot order (eacsr) so the per-layer edge pass can run in slot order
// with pure streaming reads/writes; 16B random-write RFO paid ONCE here.
__global__ void k_scatter(const int* __restrict__ ei, const float4* __restrict__ eattr,
                          int* fill, int* __restrict__ col, float4* __restrict__ eacsr){
  int idx = blockIdx.x*blockDim.x + threadIdx.x;
  if (idx < EE){
    int d = ei[EE+idx];
    int pos = atomicAdd(&fill[d],1);
    int slot = d*STRIDE + 1 + pos;
    col[slot] = ei[idx];
    eacsr[slot] = eattr[idx];
  } else if (idx < EEN){
    int n = idx-EE;
    col[n*STRIDE] = n;
  }
}

// ---------------- av (all 3 layers) + zred init, one launch ----------------
template<int F_IN,int HH,int CC>
__device__ __forceinline__ void av_one(const float* W, const float* asrc,
                                       const float* adst, float* av, int tid){
  if (tid >= HH*F_IN) return;
  int h = tid / F_IN, f = tid % F_IN;
  float s1=0.f, s2=0.f;
  for (int c=0;c<CC;c++){
    float wv = W[(size_t)(h*CC+c)*F_IN+f];
    s1 += asrc[h*CC+c]*wv;
    s2 += adst[h*CC+c]*wv;
  }
  av[tid] = s1;
  av[HH*F_IN+tid] = s2;
}
// zred layout (R11): per-head accumulators padded to their own 64B cache
// line so concurrent atomics to different heads don't serialize on one
// line. 3 layers x 4 heads x 16 floats: layer l head h at zred[l*64+h*16].
__global__ void k_av3(const float* W0, const float* as0, const float* ad0, float* av0,
                      const float* W1, const float* as1, const float* ad1, float* av1,
                      const float* W2, const float* as2, const float* ad2, float* av2,
                      float* zred){
  int tid = threadIdx.x;
  if      (blockIdx.x==0){ av_one<IN0,4,64> (W0, as0, ad0, av0, tid); if (tid<192) zred[tid]=0.f; }
  else if (blockIdx.x==1) av_one<64,4,64>  (W1, as1, ad1, av1, tid);
  else                    av_one<64,1,128> (W2, as2, ad2, av2, tid);
}

// ---------------- outer-product register-tiled GEMM + fused scores --------
template<int K,int NCOL,int HH,bool CONCAT>
__global__ __launch_bounds__(256)
void k_gemm(const float* __restrict__ xin, const int* __restrict__ jt,
            const float* __restrict__ emb, const float* __restrict__ W,
            const float* __restrict__ avp, unsigned short* __restrict__ hout,
            float* __restrict__ si, float* __restrict__ sj){
  constexpr int PITCH = 132;
  __shared__ float xT[K*PITCH];
  __shared__ float wT[K*PITCH];
  __shared__ float EMBL[CONCAT ? 17*EMBD : 1];
  int tid = threadIdx.x;
  int rbase = blockIdx.x*128, cbase = blockIdx.y*128;
  if (CONCAT){
    for (int i=tid; i<17*EMBD; i+=256) EMBL[i]=emb[i];
    __syncthreads();
    if (tid < 128){
      int row = tid;
      int gr = rbase+row; if (gr >= NN) gr = NN-1;
      float4 v = ((const float4*)xin)[gr];
      xT[0*PITCH+row]=v.x; xT[1*PITCH+row]=v.y;
      xT[2*PITCH+row]=v.z; xT[3*PITCH+row]=v.w;
      int j = jt[gr];
      #pragma unroll
      for (int k=0;k<EMBD;k++) xT[(NFEAT+k)*PITCH+row] = EMBL[j*EMBD+k];
    } else {
      int col = tid-128;
      const float4* wp = (const float4*)(W + (size_t)(cbase+col)*K);
      #pragma unroll
      for (int k4=0;k4<K/4;k4++){
        float4 v = wp[k4];
        wT[(4*k4+0)*PITCH+col]=v.x; wT[(4*k4+1)*PITCH+col]=v.y;
        wT[(4*k4+2)*PITCH+col]=v.z; wT[(4*k4+3)*PITCH+col]=v.w;
      }
    }
  } else {
    constexpr int K4 = K/4;
    for (int i=tid; i<128*K4; i+=256){
      int row = i/K4, k4 = i%K4;
      int gr = rbase+row; if (gr >= NN) gr = NN-1;
      float4 v = ((const float4*)xin)[(size_t)gr*K4 + k4];
      xT[(4*k4+0)*PITCH+row]=v.x; xT[(4*k4+1)*PITCH+row]=v.y;
      xT[(4*k4+2)*PITCH+row]=v.z; xT[(4*k4+3)*PITCH+row]=v.w;
    }
    for (int i=tid; i<128*K4; i+=256){
      int col = i/K4, k4 = i%K4;
      float4 v = ((const float4*)W)[(size_t)(cbase+col)*K4 + k4];
      wT[(4*k4+0)*PITCH+col]=v.x; wT[(4*k4+1)*PITCH+col]=v.y;
      wT[(4*k4+2)*PITCH+col]=v.z; wT[(4*k4+3)*PITCH+col]=v.w;
    }
  }
  __syncthreads();
  int lane = tid & 63, w = tid >> 6;
  int r0 = (w>>1)*64 + (lane&7)*8;
  int c0 = (w&1)*64 + (lane>>3)*8;
  float acc[8][8];
  #pragma unroll
  for (int i=0;i<8;i++)
    #pragma unroll
    for (int j=0;j<8;j++) acc[i][j]=0.f;
  #pragma unroll 4
  for (int k=0;k<K;k++){
    float a[8], b[8];
    *(float4*)&a[0] = *(const float4*)&xT[k*PITCH + r0];
    *(float4*)&a[4] = *(const float4*)&xT[k*PITCH + r0 + 4];
    *(float4*)&b[0] = *(const float4*)&wT[k*PITCH + c0];
    *(float4*)&b[4] = *(const float4*)&wT[k*PITCH + c0 + 4];
    #pragma unroll
    for (int i=0;i<8;i++)
      #pragma unroll
      for (int j=0;j<8;j++) acc[i][j] += a[i]*b[j];
  }
  if (blockIdx.y==0 && tid < 128){
    int row = tid, gr = rbase+row;
    if (gr < NN){
      #pragma unroll
      for (int h=0;h<HH;h++){
        float a=0.f, b=0.f;
        for (int k=0;k<K;k++){
          float xv = xT[k*PITCH+row];
          a += xv*avp[h*K+k];
          b += xv*avp[HH*K+h*K+k];
        }
        si[(size_t)gr*HH+h]=a;
        sj[(size_t)gr*HH+h]=b;
      }
    }
  }
  #pragma unroll
  for (int i=0;i<8;i++){
    int n = rbase + r0 + i;
    if (n < NN){
      uint4 o;
      o.x = (unsigned)f2bf(acc[i][0]) | ((unsigned)f2bf(acc[i][1])<<16);
      o.y = (unsigned)f2bf(acc[i][2]) | ((unsigned)f2bf(acc[i][3])<<16);
      o.z = (unsigned)f2bf(acc[i][4]) | ((unsigned)f2bf(acc[i][5])<<16);
      o.w = (unsigned)f2bf(acc[i][6]) | ((unsigned)f2bf(acc[i][7])<<16);
      *(uint4*)(hout + (size_t)n*NCOL + cbase + c0) = o;
    }
  }
}

// ---------------- slot-order edge pass: exp(lrelu(score)) + per-head sum ----
// R11: grid-stride over nodes (EDGE_NB blocks), z accumulated in registers
// across ~NN/(4*EDGE_NB) nodes per wave; ONE atomicAdd per head per block to
// a per-head-padded cache line. R10's 50k same-line atomics (the 164us
// serializer: 2.3% HBM + 8.5% VALU + long dur = global serialization) drop
// to 4k spread over 4 lines. Streaming shape from R10 kept: col/eacsr/pp
// all CSR-slot order, si[n] broadcast, only sj[src] is an L2 gather.
template<int HH>
__global__ __launch_bounds__(256)
void k_edge2(const int* __restrict__ col, const float4* __restrict__ eacsr,
             const int* __restrict__ fill, const float* __restrict__ We,
             const float* __restrict__ si, const float* __restrict__ sj,
             float* __restrict__ pp, float* __restrict__ zred){
  int wave = threadIdx.x>>6, lane = threadIdx.x&63;
  float z[HH];
  #pragma unroll
  for (int h=0;h<HH;h++) z[h]=0.f;
  for (int n = blockIdx.x*4 + wave; n < NN; n += EDGE_NB*4){
    int cnt = 1 + fill[n];
    if (lane < cnt){
      int slot = n*STRIDE + lane;
      int s = col[slot];
      float4 ea;
      if (lane==0){ ea = make_float4(0.f,0.f,0.f,0.f); }
      else        { ea = eacsr[slot]; }
      if (HH==4){
        float4 siv = ((const float4*)si)[n];
        float4 sjv = ((const float4*)sj)[s];
        float te[4] = {siv.x+sjv.x, siv.y+sjv.y, siv.z+sjv.z, siv.w+sjv.w};
        float pv[4];
        #pragma unroll
        for (int h=0;h<4;h++){
          float t = te[h] + ea.x*We[h*EFEAT+0] + ea.y*We[h*EFEAT+1]
                          + ea.z*We[h*EFEAT+2] + ea.w*We[h*EFEAT+3];
          t = (t>0.f)? t : 0.2f*t;
          float p = expf(t);
          z[h]+=p; pv[h]=p;
        }
        ((float4*)pp)[slot] = make_float4(pv[0],pv[1],pv[2],pv[3]);
      } else {
        float t = si[n] + sj[s]
                + ea.x*We[0] + ea.y*We[1] + ea.z*We[2] + ea.w*We[3];
        t = (t>0.f)? t : 0.2f*t;
        float p = expf(t);
        z[0]+=p;
        pp[slot] = p;
      }
    }
  }
  __shared__ float zs[4][HH];
  #pragma unroll
  for (int h=0;h<HH;h++){
    float v=z[h];
    #pragma unroll
    for (int off=32; off>0; off>>=1) v += __shfl_xor(v,off,64);
    if (lane==0) zs[wave][h]=v;
  }
  __syncthreads();
  if (threadIdx.x < HH){
    float tot = zs[0][threadIdx.x]+zs[1][threadIdx.x]
              + zs[2][threadIdx.x]+zs[3][threadIdx.x];
    atomicAdd(&zred[threadIdx.x*16], tot);   // head h -> own 64B line
  }
}

// ---------------- pull-mode aggregation, wave-per-node, bf16 gather --------
// R6-proven access shape: col (4B) + pp (CSR-ordered) stream; only h is a
// random gather. 8-edge unroll + remainder. Only the zred index changed
// (padded per-head lines).
template<int HH,int CC,bool DO_ELU>
__global__ __launch_bounds__(256)
void k_agg(const unsigned short* __restrict__ hb, const float* __restrict__ pp,
           const float* __restrict__ zred, const int* __restrict__ fill,
           const int* __restrict__ col, float* __restrict__ outp){
  constexpr int HC = HH*CC;
  constexpr int V  = HC/64;
  using LT = typename ldt<V>::T;
  int wave = threadIdx.x>>6, lane = threadIdx.x&63;
  int n = blockIdx.x*4 + wave;           // NN % 4 == 0
  int hd = (lane*V)/CC;
  float invZ = 1.0f/zred[hd*16];
  float acc[V];
  #pragma unroll
  for (int v=0;v<V;v++) acc[v]=0.f;
  auto mac = [&](float p, LT h){
    if constexpr (V==4){
      acc[0] += p*bfl(h.x); acc[1] += p*bfh(h.x);
      acc[2] += p*bfl(h.y); acc[3] += p*bfh(h.y);
    } else {
      acc[0] += p*bfl(h);   acc[1] += p*bfh(h);
    }
  };
  int beg = n*STRIDE, end = beg + 1 + fill[n];
  int i = beg;
  for (; i+8<=end; i+=8){
    int sr[8]; float p[8]; LT h[8];
    #pragma unroll
    for (int k=0;k<8;k++) sr[k]=col[i+k];
    #pragma unroll
    for (int k=0;k<8;k++)
      p[k] = (HH==4) ? pp[(size_t)(i+k)*4+hd] : pp[i+k];
    #pragma unroll
    for (int k=0;k<8;k++) h[k]=((const LT*)(hb + (size_t)sr[k]*HC))[lane];
    #pragma unroll
    for (int k=0;k<8;k++) mac(p[k], h[k]);
  }
  for (; i<end; i++){
    int sr = col[i];
    float p = (HH==4) ? pp[(size_t)i*4+hd] : pp[i];
    LT h = ((const LT*)(hb + (size_t)sr*HC))[lane];
    mac(p, h);
  }
  #pragma unroll
  for (int v=0;v<V;v++) acc[v] *= invZ;
  if (HH==4){
    #pragma unroll
    for (int off=16; off<64; off<<=1){
      #pragma unroll
      for (int v=0;v<V;v++) acc[v] += __shfl_xor(acc[v], off, 64);
    }
    if (lane < 16){
      float4 o;
      o.x=0.25f*acc[0]; o.y=0.25f*acc[1]; o.z=0.25f*acc[2]; o.w=0.25f*acc[3];
      if (DO_ELU){
        o.x = (o.x>0.f)? o.x : expm1f(o.x);
        o.y = (o.y>0.f)? o.y : expm1f(o.y);
        o.z = (o.z>0.f)? o.z : expm1f(o.z);
        o.w = (o.w>0.f)? o.w : expm1f(o.w);
      }
      ((float4*)outp)[(size_t)n*(CC/4)+lane] = o;
    }
  } else {
    float2 o; o.x=acc[0]; o.y=acc[1];
    if (DO_ELU){
      o.x = (o.x>0.f)? o.x : expm1f(o.x);
      o.y = (o.y>0.f)? o.y : expm1f(o.y);
    }
    ((float2*)outp)[(size_t)n*(CC/2)+lane] = o;
  }
}

extern "C" void kernel_launch(void* const* d_in, const int* in_sizes, int n_in,
                              void* d_out, int out_size, void* d_ws, size_t ws_size,
                              hipStream_t stream){
  const float* x    = (const float*)d_in[0];
  const int*   ei   = (const int*)d_in[1];
  const float* eatt = (const float*)d_in[2];
  const int*   jt   = (const int*)d_in[3];
  const float* emb  = (const float*)d_in[4];
  const float* W0   = (const float*)d_in[5];
  const float* as0  = (const float*)d_in[6];
  const float* ad0  = (const float*)d_in[7];
  const float* We0  = (const float*)d_in[8];
  const float* W1   = (const float*)d_in[9];
  const float* as1  = (const float*)d_in[10];
  const float* ad1  = (const float*)d_in[11];
  const float* We1  = (const float*)d_in[12];
  const float* W2   = (const float*)d_in[13];
  const float* as2  = (const float*)d_in[14];
  const float* ad2  = (const float*)d_in[15];
  const float* We2  = (const float*)d_in[16];
  float* out = (float*)d_out;

  char* p = (char*)d_ws;
  auto alloc = [&](size_t bytes)->char*{
    char* r = p; p += (bytes + 255) & ~(size_t)255; return r;
  };
  unsigned short* hbuf = (unsigned short*)alloc((size_t)NN*256*2); // 25.6 MB bf16
  float* x1     = (float*)alloc((size_t)NN*64*4);
  float* x2     = (float*)alloc((size_t)NN*64*4);
  float* si     = (float*)alloc((size_t)NN*4*4);
  float* sj     = (float*)alloc((size_t)NN*4*4);
  float* pp     = (float*)alloc((size_t)NN*STRIDE*16); // 51.2 MB CSR-slot alphas
  int*   fill   = (int*)alloc((size_t)NN*4);
  int*   col    = (int*)alloc((size_t)NN*STRIDE*4);    // 12.8 MB fixed-stride CSR
  float4* eacsr = (float4*)alloc((size_t)NN*STRIDE*16);// 51.2 MB CSR-slot eattr
  float* av0    = (float*)alloc(512*4);
  float* av1    = (float*)alloc(512*4);
  float* av2    = (float*)alloc(512*4);
  float* zred   = (float*)alloc(192*4);  // 3 layers x 4 heads x 16f (64B/line)

  k_init   <<<dim3((NN+255)/256),  256, 0, stream>>>(fill);
  k_scatter<<<dim3((EEN+255)/256), 256, 0, stream>>>(ei, (const float4*)eatt,
                                                     fill, col, eacsr);
  k_av3    <<<dim3(3),             256, 0, stream>>>(W0,as0,ad0,av0, W1,as1,ad1,av1,
                                                     W2,as2,ad2,av2, zred);

  dim3 gg01((NN+127)/128, 2);
  dim3 gg2 ((NN+127)/128, 1);
  dim3 egrid2(EDGE_NB);
  dim3 ngrid(NN/4);

  // layer 0: concat(x, emb[jt]) -> [N,4,64]
  k_gemm<IN0,256,4,true> <<<gg01, 256, 0, stream>>>(x, jt, emb, W0, av0, hbuf, si, sj);
  k_edge2<4>             <<<egrid2,256, 0, stream>>>(col, eacsr, fill, We0, si, sj, pp, zred+0);
  k_agg<4,64,true>       <<<ngrid,256, 0, stream>>>(hbuf, pp, zred+0, fill, col, x1);

  // layer 1: 64 -> [N,4,64]
  k_gemm<64,256,4,false> <<<gg01, 256, 0, stream>>>(x1, jt, emb, W1, av1, hbuf, si, sj);
  k_edge2<4>             <<<egrid2,256, 0, stream>>>(col, eacsr, fill, We1, si, sj, pp, zred+64);
  k_agg<4,64,true>       <<<ngrid,256, 0, stream>>>(hbuf, pp, zred+64, fill, col, x2);

  // layer 2: 64 -> [N,1,128], no ELU on final output
  k_gemm<64,128,1,false> <<<gg2,  256, 0, stream>>>(x2, jt, emb, W2, av2, hbuf, si, sj);
  k_edge2<1>             <<<egrid2,256, 0, stream>>>(col, eacsr, fill, We2, si, sj, pp, zred+128);
  k_agg<1,128,false>     <<<ngrid,256, 0, stream>>>(hbuf, pp, zred+128, fill, col, out);
}